// Round 1
// baseline (321.184 us; speedup 1.0000x reference)
//
#include <hip/hip_runtime.h>

// Problem constants (from reference)
#define NN        4096      // N_NEURONS
#define BATCH     4096
#define FEATN     512
#define MMAP      65536     // 256*256
#define LRC       0.005f
// 2*SIGMA^2 = 8 ;  2*FEAT = 1024

// ---------------- ws layout (bytes) ----------------
// 0     : bmuKey  (unsigned long long, init 0xFF..FF)
// 64    : sumx[4096]      (atomic accum, init 0)
// 16448 : current[512]    (atomic accum, init 0)
// 18496 : outff[512]      (atomic accum, init 0)
// 20544 : feat[512]       (direct write)
// total ~22.6 KB

// K1: column sums of sensory_input [4096 x 4096]; grid(4,128), block 256.
__global__ void hpc_colsum(const float* __restrict__ A, float* __restrict__ sumx) {
    int col = blockIdx.x * 1024 + threadIdx.x * 4;
    const float* p = A + (size_t)(blockIdx.y * 32) * NN + col;
    float4 acc = make_float4(0.f, 0.f, 0.f, 0.f);
    #pragma unroll 4
    for (int r = 0; r < 32; ++r) {
        float4 v = *reinterpret_cast<const float4*>(p);
        p += NN;
        acc.x += v.x; acc.y += v.y; acc.z += v.z; acc.w += v.w;
    }
    atomicAdd(&sumx[col + 0], acc.x);
    atomicAdd(&sumx[col + 1], acc.y);
    atomicAdd(&sumx[col + 2], acc.z);
    atomicAdd(&sumx[col + 3], acc.w);
}

// K2: current[t] = (1/4096) * sum_i sumx[i] * W_in[i][t]; grid 32, block 512.
__global__ void hpc_current(const float* __restrict__ Win, const float* __restrict__ sumx,
                            float* __restrict__ current) {
    int t  = threadIdx.x;           // 0..511
    int i0 = blockIdx.x * 128;
    float acc = 0.f;
    #pragma unroll 4
    for (int i = 0; i < 128; ++i)
        acc += sumx[i0 + i] * Win[(size_t)(i0 + i) * FEATN + t];
    atomicAdd(&current[t], acc * (1.0f / (float)BATCH));
}

// K3: outff[t] = sum_k (current[k] >= 1) * W_out[k][t]; grid 8, block 512.
__global__ void hpc_outff(const float* __restrict__ Wout, const float* __restrict__ current,
                          float* __restrict__ outff) {
    int t  = threadIdx.x;           // 0..511
    int k0 = blockIdx.x * 64;
    float acc = 0.f;
    for (int k = 0; k < 64; ++k) {
        float c = current[k0 + k];          // block-uniform
        if (c >= 1.0f)
            acc += Wout[(size_t)(k0 + k) * FEATN + t];
    }
    atomicAdd(&outff[t], acc);
}

// K4: feat[j] = relu(dot(projW[j,:], outff) + projb[j]); wave per row; grid 128, block 256.
__global__ void hpc_feat(const float* __restrict__ projW, const float* __restrict__ projb,
                         const float* __restrict__ outff, float* __restrict__ feat) {
    int lane = threadIdx.x & 63;
    int j    = blockIdx.x * 4 + (threadIdx.x >> 6);   // 0..511
    const float4* row = reinterpret_cast<const float4*>(projW + (size_t)j * FEATN);
    const float4* v   = reinterpret_cast<const float4*>(outff);
    float4 a0 = row[lane],      b0 = v[lane];
    float4 a1 = row[lane + 64], b1 = v[lane + 64];
    float s = a0.x * b0.x + a0.y * b0.y + a0.z * b0.z + a0.w * b0.w
            + a1.x * b1.x + a1.y * b1.y + a1.z * b1.z + a1.w * b1.w;
    #pragma unroll
    for (int k = 32; k >= 1; k >>= 1) s += __shfl_xor(s, k, 64);
    if (lane == 0) {
        float f = s + projb[j];
        feat[j] = f > 0.f ? f : 0.f;
    }
}

// K5: d2[m] = ||som_w[m,:] - feat||^2 ; wave per row; also grid argmin via encoded atomicMin.
// d2 is written into d_out (exactly 65536 floats). grid 16384, block 256.
__global__ void hpc_d2(const float* __restrict__ somw, const float* __restrict__ feat,
                       float* __restrict__ d2out, unsigned long long* __restrict__ bmuKey) {
    __shared__ float sf[FEATN];
    __shared__ unsigned long long smin[4];
    int tid = threadIdx.x;
    sf[tid]       = feat[tid];
    sf[tid + 256] = feat[tid + 256];
    __syncthreads();

    int wave = tid >> 6, lane = tid & 63;
    int m = blockIdx.x * 4 + wave;
    const float4* row = reinterpret_cast<const float4*>(somw + (size_t)m * FEATN);
    const float4* fv  = reinterpret_cast<const float4*>(sf);
    float4 a0 = row[lane],      f0 = fv[lane];
    float4 a1 = row[lane + 64], f1 = fv[lane + 64];
    float d, s = 0.f;
    d = a0.x - f0.x; s += d * d;
    d = a0.y - f0.y; s += d * d;
    d = a0.z - f0.z; s += d * d;
    d = a0.w - f0.w; s += d * d;
    d = a1.x - f1.x; s += d * d;
    d = a1.y - f1.y; s += d * d;
    d = a1.z - f1.z; s += d * d;
    d = a1.w - f1.w; s += d * d;
    #pragma unroll
    for (int k = 32; k >= 1; k >>= 1) s += __shfl_xor(s, k, 64);

    if (lane == 0) {
        d2out[m] = s;
        // nonneg float bits preserve order; low 32 bits = index -> ties pick lowest index
        smin[wave] = ((unsigned long long)__float_as_uint(s) << 32) | (unsigned)m;
    }
    __syncthreads();
    if (tid == 0) {
        unsigned long long k0 = smin[0];
        if (smin[1] < k0) k0 = smin[1];
        if (smin[2] < k0) k0 = smin[2];
        if (smin[3] < k0) k0 = smin[3];
        // stale-read pre-filter: only touch the hot atomic if we might improve it
        if (k0 < *(volatile unsigned long long*)bmuKey)
            atomicMin(bmuKey, k0);
    }
}

// K6: out[m] = exp(-d2[m]*(1-LR*nb(m))^6 / 1024), nb = exp(-grid_dist2/8).
// BMU is invariant across the 3 reference iterations (factor at bmu is strictly
// the smallest), so the 3 updates collapse to the ^6 power. grid 256, block 256.
__global__ void hpc_final(float* __restrict__ out, const unsigned long long* __restrict__ bmuKey) {
    int m = blockIdx.x * 256 + threadIdx.x;
    unsigned long long key = *bmuKey;
    int bmu = (int)(key & 0xFFFFFFFFull);
    float dy = (float)(m >> 8)  - (float)(bmu >> 8);
    float dx = (float)(m & 255) - (float)(bmu & 255);
    float g2 = dy * dy + dx * dx;
    float nb = expf(-g2 * 0.125f);          // 2*SIGMA^2 = 8
    float fac = 1.0f - LRC * nb;
    float f2 = fac * fac;
    float f6 = f2 * f2 * f2;                // 3 iterations -> (1-LR*nb)^6 on d2
    float d2 = out[m];
    out[m] = expf(-(d2 * f6) * (1.0f / 1024.0f));   // 2*FEAT = 1024
}

extern "C" void kernel_launch(void* const* d_in, const int* in_sizes, int n_in,
                              void* d_out, int out_size, void* d_ws, size_t ws_size,
                              hipStream_t stream) {
    const float* sensory = (const float*)d_in[0];
    const float* Win     = (const float*)d_in[1];
    const float* Wout    = (const float*)d_in[2];
    const float* projW   = (const float*)d_in[3];
    const float* projb   = (const float*)d_in[4];
    const float* somw    = (const float*)d_in[5];
    float* out = (float*)d_out;

    char* ws = (char*)d_ws;
    unsigned long long* bmuKey = (unsigned long long*)ws;
    float* sumx    = (float*)(ws + 64);
    float* current = (float*)(ws + 16448);
    float* outff   = (float*)(ws + 18496);
    float* feat    = (float*)(ws + 20544);

    hipMemsetAsync(bmuKey, 0xFF, 8, stream);                 // argmin identity
    hipMemsetAsync(sumx, 0, 16384 + 2048 + 2048, stream);    // zero accumulators

    hipLaunchKernelGGL(hpc_colsum,  dim3(4, 128), dim3(256), 0, stream, sensory, sumx);
    hipLaunchKernelGGL(hpc_current, dim3(32),     dim3(512), 0, stream, Win, sumx, current);
    hipLaunchKernelGGL(hpc_outff,   dim3(8),      dim3(512), 0, stream, Wout, current, outff);
    hipLaunchKernelGGL(hpc_feat,    dim3(128),    dim3(256), 0, stream, projW, projb, outff, feat);
    hipLaunchKernelGGL(hpc_d2,      dim3(16384),  dim3(256), 0, stream, somw, feat, out, bmuKey);
    hipLaunchKernelGGL(hpc_final,   dim3(256),    dim3(256), 0, stream, out, bmuKey);
}

// Round 2
// 277.288 us; speedup vs baseline: 1.1583x; 1.1583x over previous
//
#include <hip/hip_runtime.h>

#define NN        4096      // N_NEURONS == BATCH
#define FEATN     512
#define LRC       0.005f
// 2*SIGMA^2 = 8 ; 2*FEAT = 1024

// ---------------- ws layout (bytes) ----------------
// 0      : sumx[4096]     (batch-mean of sensory_input, pre-scaled 1/4096)
// 16384  : current[512]   (atomic accum, zeroed by k_colsum_fin)
// 18432  : outff[512]     (atomic accum, zeroed by k_colsum_fin)
// 20480  : feat[512]
// 22528  : bmuKey (ull, set to ~0 by k_colsum_fin)
// 24576  : partial[chunks*4096] floats (colsum partials)

// K1a: partial column sums of sensory_input [4096 x 4096].
// grid (4, chunks), block 256; block (bx,by) sums rows [by*rpb, by*rpb+rpb)
// for columns bx*1024 + tid*4 .. +3. No atomics.
__global__ void k_colsum_part(const float* __restrict__ A, float* __restrict__ partial, int rpb) {
    int col = blockIdx.x * 1024 + threadIdx.x * 4;
    const float* p = A + (size_t)blockIdx.y * rpb * NN + col;
    float4 acc = make_float4(0.f, 0.f, 0.f, 0.f);
    for (int r = 0; r < rpb; r += 8) {
        #pragma unroll
        for (int u = 0; u < 8; ++u) {
            float4 v = *reinterpret_cast<const float4*>(p + (size_t)(r + u) * NN);
            acc.x += v.x; acc.y += v.y; acc.z += v.z; acc.w += v.w;
        }
    }
    *reinterpret_cast<float4*>(partial + (size_t)blockIdx.y * NN + col) = acc;
}

// K1b: fold partials -> sumx (scaled by 1/4096); also init accumulators + bmuKey.
// grid 16, block 256.
__global__ void k_colsum_fin(const float* __restrict__ partial, float* __restrict__ sumx,
                             float* __restrict__ current, float* __restrict__ outff,
                             unsigned long long* __restrict__ bmuKey, int chunks) {
    int col = blockIdx.x * 256 + threadIdx.x;
    float acc = 0.f;
    #pragma unroll 8
    for (int p = 0; p < chunks; ++p)
        acc += partial[(size_t)p * NN + col];
    sumx[col] = acc * (1.0f / 4096.0f);
    if (blockIdx.x == 0) { current[threadIdx.x] = 0.f; current[threadIdx.x + 256] = 0.f; }
    if (blockIdx.x == 1) { outff[threadIdx.x]   = 0.f; outff[threadIdx.x + 256]   = 0.f; }
    if (blockIdx.x == 2 && threadIdx.x == 0) *bmuKey = ~0ull;
}

// K2: current[t] = sum_i sumx[i] * W_in[i][t]  (sumx pre-scaled). grid (64,2), block 256.
__global__ void k_current(const float* __restrict__ Win, const float* __restrict__ sumx,
                          float* __restrict__ current) {
    int t  = blockIdx.y * 256 + threadIdx.x;
    int i0 = blockIdx.x * 64;
    float acc = 0.f;
    #pragma unroll 8
    for (int i = 0; i < 64; ++i)
        acc += sumx[i0 + i] * Win[(size_t)(i0 + i) * FEATN + t];
    atomicAdd(&current[t], acc);
}

// K3: outff[t] = sum_k (current[k] >= 1) * W_out[k][t]. grid (16,2), block 256.
__global__ void k_outff(const float* __restrict__ Wout, const float* __restrict__ current,
                        float* __restrict__ outff) {
    int t  = blockIdx.y * 256 + threadIdx.x;
    int k0 = blockIdx.x * 32;
    float acc = 0.f;
    for (int k = 0; k < 32; ++k) {
        if (current[k0 + k] >= 1.0f)            // block-uniform branch
            acc += Wout[(size_t)(k0 + k) * FEATN + t];
    }
    atomicAdd(&outff[t], acc);
}

// K4: feat[j] = relu(dot(projW[j,:], outff) + projb[j]); wave per row; grid 128, block 256.
__global__ void k_feat(const float* __restrict__ projW, const float* __restrict__ projb,
                       const float* __restrict__ outff, float* __restrict__ feat) {
    int lane = threadIdx.x & 63;
    int j    = blockIdx.x * 4 + (threadIdx.x >> 6);
    const float4* row = reinterpret_cast<const float4*>(projW + (size_t)j * FEATN);
    const float4* v   = reinterpret_cast<const float4*>(outff);
    float4 a0 = row[lane],      b0 = v[lane];
    float4 a1 = row[lane + 64], b1 = v[lane + 64];
    float s = a0.x * b0.x + a0.y * b0.y + a0.z * b0.z + a0.w * b0.w
            + a1.x * b1.x + a1.y * b1.y + a1.z * b1.z + a1.w * b1.w;
    #pragma unroll
    for (int k = 32; k >= 1; k >>= 1) s += __shfl_xor(s, k, 64);
    if (lane == 0) {
        float f = s + projb[j];
        feat[j] = f > 0.f ? f : 0.f;
    }
}

// K5: d2[m] = ||som_w[m,:] - feat||^2, 8 rows per wave (16 KB of loads in flight
// before any reduction). Writes d2 into d_out; grid-wide argmin via encoded
// atomicMin (stale-read pre-filter). grid 2048, block 256.
__global__ void k_d2(const float* __restrict__ somw, const float* __restrict__ feat,
                     float* __restrict__ d2out, unsigned long long* __restrict__ bmuKey) {
    __shared__ float sf[FEATN];
    __shared__ unsigned long long smin[4];
    int tid = threadIdx.x;
    sf[tid]       = feat[tid];
    sf[tid + 256] = feat[tid + 256];
    __syncthreads();

    int wave = tid >> 6, lane = tid & 63;
    int base = blockIdx.x * 32 + wave * 8;          // 8 consecutive rows per wave
    const float4* fv = reinterpret_cast<const float4*>(sf);
    float4 f0 = fv[lane], f1 = fv[lane + 64];

    float4 va[8], vb[8];
    #pragma unroll
    for (int r = 0; r < 8; ++r) {
        const float4* row = reinterpret_cast<const float4*>(somw + (size_t)(base + r) * FEATN);
        va[r] = row[lane];
        vb[r] = row[lane + 64];
    }

    float s[8];
    #pragma unroll
    for (int r = 0; r < 8; ++r) {
        float d, acc = 0.f;
        d = va[r].x - f0.x; acc += d * d;
        d = va[r].y - f0.y; acc += d * d;
        d = va[r].z - f0.z; acc += d * d;
        d = va[r].w - f0.w; acc += d * d;
        d = vb[r].x - f1.x; acc += d * d;
        d = vb[r].y - f1.y; acc += d * d;
        d = vb[r].z - f1.z; acc += d * d;
        d = vb[r].w - f1.w; acc += d * d;
        s[r] = acc;
    }
    #pragma unroll
    for (int r = 0; r < 8; ++r) {
        #pragma unroll
        for (int k = 32; k >= 1; k >>= 1) s[r] += __shfl_xor(s[r], k, 64);
    }

    if (lane == 0) {
        float4 o0 = make_float4(s[0], s[1], s[2], s[3]);
        float4 o1 = make_float4(s[4], s[5], s[6], s[7]);
        *reinterpret_cast<float4*>(d2out + base)     = o0;
        *reinterpret_cast<float4*>(d2out + base + 4) = o1;
        unsigned long long kmin = ~0ull;
        #pragma unroll
        for (int r = 0; r < 8; ++r) {
            unsigned long long key =
                ((unsigned long long)__float_as_uint(s[r]) << 32) | (unsigned)(base + r);
            if (key < kmin) kmin = key;
        }
        smin[wave] = kmin;
    }
    __syncthreads();
    if (tid == 0) {
        unsigned long long k0 = smin[0];
        if (smin[1] < k0) k0 = smin[1];
        if (smin[2] < k0) k0 = smin[2];
        if (smin[3] < k0) k0 = smin[3];
        if (k0 < *(volatile unsigned long long*)bmuKey)
            atomicMin(bmuKey, k0);
    }
}

// K6: out[m] = exp(-d2[m]*(1-LR*nb(m))^6 / 1024). BMU invariant across the 3
// reference iterations (bmu shrinks by the strictly-smallest factor). grid 256.
__global__ void k_final(float* __restrict__ out, const unsigned long long* __restrict__ bmuKey) {
    int m = blockIdx.x * 256 + threadIdx.x;
    unsigned long long key = *bmuKey;
    int bmu = (int)(key & 0xFFFFFFFFull);
    float dy = (float)(m >> 8)  - (float)(bmu >> 8);
    float dx = (float)(m & 255) - (float)(bmu & 255);
    float g2 = dy * dy + dx * dx;
    float nb = expf(-g2 * 0.125f);          // 2*SIGMA^2 = 8
    float fac = 1.0f - LRC * nb;
    float f2 = fac * fac;
    float f6 = f2 * f2 * f2;                // 3 iterations -> (1-LR*nb)^6 on d2
    float d2 = out[m];
    out[m] = expf(-(d2 * f6) * (1.0f / 1024.0f));   // 2*FEAT = 1024
}

extern "C" void kernel_launch(void* const* d_in, const int* in_sizes, int n_in,
                              void* d_out, int out_size, void* d_ws, size_t ws_size,
                              hipStream_t stream) {
    const float* sensory = (const float*)d_in[0];
    const float* Win     = (const float*)d_in[1];
    const float* Wout    = (const float*)d_in[2];
    const float* projW   = (const float*)d_in[3];
    const float* projb   = (const float*)d_in[4];
    const float* somw    = (const float*)d_in[5];
    float* out = (float*)d_out;

    char* ws = (char*)d_ws;
    float* sumx    = (float*)(ws);
    float* current = (float*)(ws + 16384);
    float* outff   = (float*)(ws + 18432);
    float* feat    = (float*)(ws + 20480);
    unsigned long long* bmuKey = (unsigned long long*)(ws + 22528);
    float* partial = (float*)(ws + 24576);

    // pick largest partial-chunk count that fits the workspace (ws_size is
    // constant across calls, so this host-side branch is graph-safe)
    int chunks = 128;
    while (chunks > 16 && ws_size < (size_t)24576 + (size_t)chunks * NN * 4) chunks >>= 1;
    int rpb = NN / chunks;

    hipLaunchKernelGGL(k_colsum_part, dim3(4, chunks), dim3(256), 0, stream, sensory, partial, rpb);
    hipLaunchKernelGGL(k_colsum_fin,  dim3(16),        dim3(256), 0, stream, partial, sumx, current, outff, bmuKey, chunks);
    hipLaunchKernelGGL(k_current,     dim3(64, 2),     dim3(256), 0, stream, Win, sumx, current);
    hipLaunchKernelGGL(k_outff,       dim3(16, 2),     dim3(256), 0, stream, Wout, current, outff);
    hipLaunchKernelGGL(k_feat,        dim3(128),       dim3(256), 0, stream, projW, projb, outff, feat);
    hipLaunchKernelGGL(k_d2,          dim3(2048),      dim3(256), 0, stream, somw, feat, out, bmuKey);
    hipLaunchKernelGGL(k_final,       dim3(256),       dim3(256), 0, stream, out, bmuKey);
}